// Round 4
// baseline (25829.984 us; speedup 1.0000x reference)
//
#include <hip/hip_runtime.h>
#include <math.h>

#define TT 512
#define BB 64
#define HH 1024
#define KK 2048          // IN + H
#define NWGL 128         // WGs per layer
#define ROWS 8           // H rows per WG
#define RING_D 8         // h0 ring depth
#define BH (BB*HH)       // 65536 floats per timestep
#define WSTRIDE 76       // staging row stride (floats): 16B-aligned, 2-way-free banks

// LDS layout (floats):
//   Wt    [KK][8]           = 16384  (64 KB, weights TRANSPOSED: Wt[k][r], resident)
//   buf   [4 waves][64][76] = 19456  (76 KB, UN-transposed [b][k] chunk staging)
//   parts [4][64][ROWS]     = 2048   (8 KB, cross-wave partial sums)
#define LDS_FLOATS (16384 + 4*64*WSTRIDE + 2048)   // 37888 floats = 148 KB

typedef float floatx4 __attribute__((ext_vector_type(4)));

// ---------------------------------------------------------------------------
// R4: R3 fixed the spills (VGPR 256->116, WRITE 2.6e8->2.7e5 KB, 185->22.6ms).
// Counters now: HBM 1%, VALUBusy 25%, 1 wave/SIMD. Arithmetic says the LDS
// pipe is the bottleneck: old inner loop = 8 ds_read_b128 (weights, broadcast
// but still 12cyc/1024B each) + 4 ds_read_b32 per 32 v_fma -> ~119 LDS cyc per
// 64 VALU cyc -> 61k LDS cyc/CU-step = 25us of the 44us step.
//
// New inner structure (sync/coherence protocol UNCHANGED from R3):
//  * lane = (b16, g): 4 b's + all 8 rows per lane (acc[4][8]), k-interleaved
//    by g = lane>>4 (lane handles k = 4j+g). One weight read now feeds
//    4b x 8r: per k-step just 2 b128 (Wt[k][0..7], 16-way broadcast,
//    banks 8g = {0,8,16,24} conflict-free) + 4 b32 in-reads (2-way, free).
//    LDS 47 cyc < VALU 64 cyc per k-step.
//  * weights transposed in LDS: Wt[k][8] (row-major-by-k, 32B rows).
//  * staging UN-transposed [b][WSTRIDE=76]: 16 b128 writes (was 64 b32+transpose).
//  * g-reduce: 2 x __shfl_xor (16,32) once per step; slot-select via cndmask
//    ladder (static acc indices only -- rule #20).
// ---------------------------------------------------------------------------

__device__ __forceinline__ void spin_ge(int* p, int target) {
    int it = 0;
    while (__hip_atomic_load(p, __ATOMIC_RELAXED, __HIP_MEMORY_SCOPE_AGENT) < target) {
        __builtin_amdgcn_s_sleep(4);
        if (++it > (1 << 21)) return;  // failsafe: fail loud (absmax), never hang
    }
}

// Agent-scope (sc1) scalar store: write-through to the coherence point.
__device__ __forceinline__ void st_agent(float* p, float v) {
    __hip_atomic_store(p, v, __ATOMIC_RELAXED, __HIP_MEMORY_SCOPE_AGENT);
}

#define FMA8(s, iv) \
    acc[s][0] += wA.x*(iv); acc[s][1] += wA.y*(iv); acc[s][2] += wA.z*(iv); acc[s][3] += wA.w*(iv); \
    acc[s][4] += wB.x*(iv); acc[s][5] += wB.y*(iv); acc[s][6] += wB.z*(iv); acc[s][7] += wB.w*(iv);

// Stage one 1024-wide half (this wave's 256-k quarter, 4 chunks of 64) into LDS
// as raw [b][k] rows (stride WSTRIDE), then accumulate 4b x 8r with k-interleave.
template<bool BYPASS>
__device__ __forceinline__ void stage_and_accum(
    const float* __restrict__ src,   // [BB][1024], row-major
    const float* __restrict__ Wt,    // LDS [KK][8] transposed weights
    float* __restrict__ bufW,        // this wave's [64][WSTRIDE] region
    int kq,                          // wave quarter offset: 256*wave
    int wof,                         // W k-offset for this half: 0 or 1024
    int lane,
    float acc[4][8])
{
    const int bsub = lane >> 4;          // 0..3 (also the k-group g)
    const int kk4  = (lane & 15) * 4;    // 0..60
    const int b16  = lane & 15;
    const int g    = bsub;
    #pragma unroll 1                     // no cross-chunk load hoisting (VGPR cap!)
    for (int c = 0; c < 4; ++c) {
        const int k0 = kq + c * 64;
        if (BYPASS) {
            #pragma unroll 1             // two bursts of 8: cap live staging regs
            for (int hf = 0; hf < 2; ++hf) {
                floatx4 v[8];
                #pragma unroll
                for (int i = 0; i < 8; ++i) {
                    const float* p = src + ((hf * 8 + i) * 4 + bsub) * 1024 + k0 + kk4;
                    asm volatile("global_load_dwordx4 %0, %1, off sc1"
                                 : "=v"(v[i]) : "v"(p));
                }
                asm volatile("s_waitcnt vmcnt(0)" ::: "memory");
                __builtin_amdgcn_sched_barrier(0);   // pin: no consumer before wait
                #pragma unroll
                for (int i = 0; i < 8; ++i) {
                    const int b = (hf * 8 + i) * 4 + bsub;
                    *(float4*)(bufW + b * WSTRIDE + kk4) =
                        make_float4(v[i][0], v[i][1], v[i][2], v[i][3]);
                }
            }
        } else {
            #pragma unroll
            for (int i = 0; i < 16; ++i) {
                const int b = i * 4 + bsub;
                const float4 v = *(const float4*)(src + b * 1024 + k0 + kk4);
                *(float4*)(bufW + b * WSTRIDE + kk4) = v;
            }
        }
        // Per-wave LDS ops are in order: no barrier needed (per-wave buffer).
        // Compute: 16 k-steps; this lane handles k = k0 + 4j + g.
        const float* wt = Wt + (size_t)(wof + k0 + g) * 8;   // + j*32 per step
        const float* bw = bufW + b16 * WSTRIDE + g;          // + j*4  per step
        #pragma unroll 4
        for (int j = 0; j < 16; ++j) {
            const float4 wA = *(const float4*)(wt + j * 32);      // Wt[k][0..3]
            const float4 wB = *(const float4*)(wt + j * 32 + 4);  // Wt[k][4..7]
            const float i0 = bw[j * 4];                            // b16
            const float i1 = bw[j * 4 + 16 * WSTRIDE];             // b16+16
            const float i2 = bw[j * 4 + 32 * WSTRIDE];             // b16+32
            const float i3 = bw[j * 4 + 48 * WSTRIDE];             // b16+48
            FMA8(0, i0) FMA8(1, i1) FMA8(2, i2) FMA8(3, i3)
        }
    }
}

extern "C" __global__ void rnn_init(int* __restrict__ c) {
    const int i = blockIdx.x * blockDim.x + threadIdx.x;
    if (i < 1024) c[i] = 0;
}

extern "C" __global__ void __launch_bounds__(256, 1)
rnn_persist(const float* __restrict__ x,      // [T][B][IN]
            const float* __restrict__ h0init, // [2][B][H]
            const float* __restrict__ Wih0, const float* __restrict__ bih0,
            const float* __restrict__ Whh0, const float* __restrict__ bhh0,
            const float* __restrict__ Wih1, const float* __restrict__ bih1,
            const float* __restrict__ Whh1, const float* __restrict__ bhh1,
            float* __restrict__ out,          // [T][B][H] then [2][B][H]
            int* __restrict__ c0, int* __restrict__ c1,
            float* __restrict__ ring)         // [RING_D][B][H]
{
    extern __shared__ float lds[];
    float* Wt    = lds;                      // 16384 floats
    float* buf   = lds + ROWS * KK;          // 4*64*WSTRIDE
    float* parts = buf + 4 * 64 * WSTRIDE;   // 4*64*8

    const int wg   = blockIdx.x;
    const bool isL1 = (wg >= NWGL);
    const int g    = isL1 ? wg - NWGL : wg;
    const int rbase = g * ROWS;
    const int tid  = threadIdx.x;
    const int wv   = tid >> 6;
    const int lane = tid & 63;
    const int kq   = wv * 256;
    float* bufW = buf + wv * (64 * WSTRIDE);

    // Load this WG's weight rows into LDS once, TRANSPOSED: Wt[k][r].
    const float* Wa = isL1 ? Wih1 : Wih0;    // k-half 0 (input half)
    const float* Wb = isL1 ? Whh1 : Whh0;    // k-half 1 (recurrent half)
    for (int idx = tid; idx < ROWS * 1024; idx += 256) {
        const int r = idx >> 10;
        const int k = idx & 1023;
        Wt[(size_t)k * 8 + r]          = Wa[(size_t)(rbase + r) * HH + k];
        Wt[(size_t)(1024 + k) * 8 + r] = Wb[(size_t)(rbase + r) * HH + k];
    }
    const int er = tid & 7;  // output row (same for tid and tid+256)
    const float bsum = isL1 ? (bih1[rbase + er] + bhh1[rbase + er])
                            : (bih0[rbase + er] + bhh0[rbase + er]);
    __syncthreads();

    const int gk = lane >> 4;   // this lane's k-group (for the slot select)

    for (int t = 0; t < TT; ++t) {
        float acc[4][8];
        #pragma unroll
        for (int s = 0; s < 4; ++s)
            #pragma unroll
            for (int r = 0; r < 8; ++r) acc[s][r] = 0.f;

        if (!isL1) {
            // Phase A: x[t] half — no dependency, hides the wait below.
            stage_and_accum<false>(x + (size_t)t * BH, Wt, bufW, kq, 0, lane, acc);
            if (tid == 0) {
                if (t >= 1)      spin_ge(c0 + (t - 1), NWGL);      // h0[t-1] ready
                if (t >= RING_D) spin_ge(c1 + (t - RING_D), NWGL); // ring slot reusable
            }
            __syncthreads();
            // Phase B: h0[t-1] half (recurrent, W_hh0 => wof 1024), sc1 reads
            const float* hp = (t == 0) ? h0init
                                       : ring + (size_t)((t - 1) % RING_D) * BH;
            stage_and_accum<true>(hp, Wt, bufW, kq, 1024, lane, acc);
        } else {
            if (tid == 0 && t >= 1) {
                spin_ge(c1 + (t - 1), NWGL);   // h1[t-1] ready
            }
            __syncthreads();
            // Phase A: h1[t-1] half (recurrent, W_hh1 => wof 1024), sc1 reads
            const float* hp = (t == 0) ? (h0init + BH)
                                       : (out + (size_t)(t - 1) * BH);
            stage_and_accum<true>(hp, Wt, bufW, kq, 1024, lane, acc);
            if (tid == 0) {
                spin_ge(c0 + t, NWGL);         // h0[t] ready
            }
            __syncthreads();
            // Phase B: h0[t] half (input half, W_ih1 => wof 0), sc1 reads
            stage_and_accum<true>(ring + (size_t)(t % RING_D) * BH, Wt, bufW, kq, 0, lane, acc);
        }

        // Reduce over the 4 k-groups: lanes differing in bits 4,5 hold partials
        // of the same (b-slot, r). After both rounds every lane has full sums.
        float outv[8];
        #pragma unroll
        for (int r = 0; r < 8; ++r) {
            #pragma unroll
            for (int s = 0; s < 4; ++s) {
                float v = acc[s][r];
                v += __shfl_xor(v, 16, 64);
                v += __shfl_xor(v, 32, 64);
                acc[s][r] = v;
            }
            // slot-select s == gk with static indices (rule #20: no runtime idx)
            float v = acc[0][r];
            if (gk == 1) v = acc[1][r];
            if (gk == 2) v = acc[2][r];
            if (gk == 3) v = acc[3][r];
            outv[r] = v;
        }

        // Cross-wave reduction: partials [w][b][r]; this lane's b == lane.
        float* pw = parts + (size_t)(wv * 64 + lane) * ROWS;
        *(float4*)(pw + 0) = make_float4(outv[0], outv[1], outv[2], outv[3]);
        *(float4*)(pw + 4) = make_float4(outv[4], outv[5], outv[6], outv[7]);
        __syncthreads();

        for (int o = tid; o < 512; o += 256) {
            const int b = o >> 3;
            const int r = o & 7;
            const float s = parts[o] + parts[o + 512] + parts[o + 1024] + parts[o + 1536] + bsum;
            const float hv = tanhf(s);
            const int col = rbase + r;
            if (!isL1) {
                st_agent(ring + (size_t)(t % RING_D) * BH + b * HH + col, hv);
                if (t == TT - 1) st_agent(out + (size_t)TT * BH + b * HH + col, hv);      // h0_n
            } else {
                st_agent(out + (size_t)t * BH + b * HH + col, hv);                        // outputs
                if (t == TT - 1) st_agent(out + (size_t)TT * BH + BH + b * HH + col, hv); // h1_n
            }
        }
        // __syncthreads drains vmcnt(0) per wave before s_barrier => after the
        // barrier ALL waves' sc1 write-throughs are at the coherence point.
        __syncthreads();
        if (tid == 0) {
            asm volatile("s_waitcnt vmcnt(0)" ::: "memory");  // belt-and-braces
            __hip_atomic_fetch_add(isL1 ? (c1 + t) : (c0 + t), 1,
                                   __ATOMIC_RELAXED, __HIP_MEMORY_SCOPE_AGENT);
        }
    }
}

extern "C" void kernel_launch(void* const* d_in, const int* in_sizes, int n_in,
                              void* d_out, int out_size, void* d_ws, size_t ws_size,
                              hipStream_t stream) {
    const float* x    = (const float*)d_in[0];
    const float* h0i  = (const float*)d_in[1];
    const float* Wih0 = (const float*)d_in[2];
    const float* bih0 = (const float*)d_in[3];
    const float* Whh0 = (const float*)d_in[4];
    const float* bhh0 = (const float*)d_in[5];
    const float* Wih1 = (const float*)d_in[6];
    const float* bih1 = (const float*)d_in[7];
    const float* Whh1 = (const float*)d_in[8];
    const float* bhh1 = (const float*)d_in[9];
    float* out = (float*)d_out;

    int*   c0   = (int*)d_ws;             // [512]
    int*   c1   = c0 + 512;               // [512]
    float* ring = (float*)((char*)d_ws + 8192);  // [RING_D][B][H]

    (void)hipFuncSetAttribute((const void*)rnn_persist,
                              hipFuncAttributeMaxDynamicSharedMemorySize,
                              LDS_FLOATS * 4);

    rnn_init<<<4, 256, 0, stream>>>(c0);
    rnn_persist<<<256, 256, LDS_FLOATS * 4, stream>>>(
        x, h0i, Wih0, bih0, Whh0, bhh0, Wih1, bih1, Whh1, bhh1,
        out, c0, c1, ring);
}

// Round 5
// 13369.453 us; speedup vs baseline: 1.9320x; 1.9320x over previous
//
#include <hip/hip_runtime.h>
#include <math.h>

#define TT 512
#define BB 64
#define HH 1024
#define KK 2048          // IN + H
#define NWGL 128         // WGs per layer
#define ROWS 8           // H rows per WG
#define RING_D 8         // h0 ring depth
#define BH (BB*HH)       // 65536 floats per timestep
#define WSTRIDE 76       // staging row stride (floats): 16B-aligned, 2-way-free banks
#define NSH 8            // counter shards per layer-event
#define SHTGT (NWGL/NSH) // 16 WGs per shard

// LDS layout (floats):
//   Wt    [KK][8]           = 16384  (64 KB, weights TRANSPOSED: Wt[k][r], resident)
//   buf   [4 waves][64][76] = 19456  (76 KB, UN-transposed [b][k] chunk staging)
//   parts [4][64][ROWS]     = 2048   (8 KB, cross-wave partial sums)
#define LDS_FLOATS (16384 + 4*64*WSTRIDE + 2048)   // 148 KB

typedef float floatx4 __attribute__((ext_vector_type(4)));

// ---------------------------------------------------------------------------
// R5: R4's LDS restructure LOWERED VALUBusy (25->12%) but dur got WORSE
// (22.6->25.8ms). With HBM 1%, VALU 12%, LDS ~20%, 1 wave/SIMD: the kernel is
// LATENCY-bound on the sync fabric, not throughput-bound anywhere.
//   (a) counter storms: 128 same-line agent RMWs per step (serialized at the
//       coherence point) + 256 WGs polling that line every ~256 cyc.
//   (b) sc1 staging drains vmcnt(0) per 8-load burst: 8 serial ~700cyc
//       fabric round-trips per half, nothing hiding them.
// Fix: (1) 8-way sharded counters (16 RMWs/shard; 8 parallel pollers),
//      (2) s_sleep(16) poll backoff,
//      (3) ping-pong vA/vB staging with counted vmcnt(16): 1 exposed
//          round-trip per half instead of 8. Compute core unchanged from R4.
// ---------------------------------------------------------------------------

__device__ __forceinline__ void spin_ge(int* p, int target) {
    int it = 0;
    while (__hip_atomic_load(p, __ATOMIC_RELAXED, __HIP_MEMORY_SCOPE_AGENT) < target) {
        __builtin_amdgcn_s_sleep(16);
        if (++it > (1 << 16)) return;  // failsafe: fail loud (absmax), never hang
    }
}

// Agent-scope (sc1) scalar store: write-through to the coherence point.
__device__ __forceinline__ void st_agent(float* p, float v) {
    __hip_atomic_store(p, v, __ATOMIC_RELAXED, __HIP_MEMORY_SCOPE_AGENT);
}

#define FMA8(s, iv) \
    acc[s][0] += wA.x*(iv); acc[s][1] += wA.y*(iv); acc[s][2] += wA.z*(iv); acc[s][3] += wA.w*(iv); \
    acc[s][4] += wB.x*(iv); acc[s][5] += wB.y*(iv); acc[s][6] += wB.z*(iv); acc[s][7] += wB.w*(iv);

// Write one staged chunk (16 float4 regs) to LDS and run its 16 k-steps.
#define STAGE_WRITE_COMPUTE(v, c) do {                                         \
    const int k0_ = kq + (c) * 64;                                             \
    _Pragma("unroll")                                                          \
    for (int i = 0; i < 16; ++i) {                                             \
        const int b = i * 4 + bsub;                                            \
        *(float4*)(bufW + b * WSTRIDE + kk4) =                                 \
            make_float4(v[i][0], v[i][1], v[i][2], v[i][3]);                   \
    }                                                                          \
    const float* wt = Wt + (size_t)(wof + k0_ + g) * 8;                        \
    const float* bw = bufW + b16 * WSTRIDE + g;                                \
    _Pragma("unroll 4")                                                        \
    for (int j = 0; j < 16; ++j) {                                             \
        const float4 wA = *(const float4*)(wt + j * 32);                       \
        const float4 wB = *(const float4*)(wt + j * 32 + 4);                   \
        const float i0 = bw[j * 4];                                            \
        const float i1 = bw[j * 4 + 16 * WSTRIDE];                             \
        const float i2 = bw[j * 4 + 32 * WSTRIDE];                             \
        const float i3 = bw[j * 4 + 48 * WSTRIDE];                             \
        FMA8(0, i0) FMA8(1, i1) FMA8(2, i2) FMA8(3, i3)                        \
    }                                                                          \
} while (0)

#define ISSUE16(v, c) do {                                                     \
    _Pragma("unroll")                                                          \
    for (int i = 0; i < 16; ++i) {                                             \
        const float* p = src + (i * 4 + bsub) * 1024 + kq + (c) * 64 + kk4;    \
        asm volatile("global_load_dwordx4 %0, %1, off sc1"                     \
                     : "=v"(v[i]) : "v"(p));                                   \
    }                                                                          \
} while (0)

// Stage one 1024-wide half (this wave's 256-k quarter, 4 chunks of 64) into LDS
// as raw [b][k] rows (stride WSTRIDE), then accumulate 4b x 8r with k-interleave.
// BYPASS: sc1 reads, ping-pong pipelined with counted vmcnt (1 exposed latency).
template<bool BYPASS>
__device__ __forceinline__ void stage_and_accum(
    const float* __restrict__ src,   // [BB][1024], row-major
    const float* __restrict__ Wt,    // LDS [KK][8] transposed weights
    float* __restrict__ bufW,        // this wave's [64][WSTRIDE] region
    int kq,                          // wave quarter offset: 256*wave
    int wof,                         // W k-offset for this half: 0 or 1024
    int lane,
    float acc[4][8])
{
    const int bsub = lane >> 4;          // 0..3 (also the k-group g)
    const int kk4  = (lane & 15) * 4;    // 0..60
    const int b16  = lane & 15;
    const int g    = bsub;
    if (BYPASS) {
        floatx4 vA[16], vB[16];          // static ping-pong (rule #20: no runtime idx)
        ISSUE16(vA, 0);                                  // A(c0) in flight
        ISSUE16(vB, 1);                                  // +B(c1): 32 out
        asm volatile("s_waitcnt vmcnt(16)" ::: "memory");  // A(c0) arrived
        __builtin_amdgcn_sched_barrier(0);
        STAGE_WRITE_COMPUTE(vA, 0);                      // B(c1) hides under this
        ISSUE16(vA, 2);                                  // +A(c2): 32 out
        asm volatile("s_waitcnt vmcnt(16)" ::: "memory");  // B(c1) arrived
        __builtin_amdgcn_sched_barrier(0);
        STAGE_WRITE_COMPUTE(vB, 1);                      // A(c2) hides under this
        ISSUE16(vB, 3);                                  // +B(c3): 32 out
        asm volatile("s_waitcnt vmcnt(16)" ::: "memory");  // A(c2) arrived
        __builtin_amdgcn_sched_barrier(0);
        STAGE_WRITE_COMPUTE(vA, 2);                      // B(c3) hides under this
        asm volatile("s_waitcnt vmcnt(0)" ::: "memory");   // B(c3) arrived
        __builtin_amdgcn_sched_barrier(0);
        STAGE_WRITE_COMPUTE(vB, 3);
    } else {
        #pragma unroll 1                 // no cross-chunk load hoisting (VGPR cap!)
        for (int c = 0; c < 4; ++c) {
            const int k0 = kq + c * 64;
            floatx4 vc[16];
            #pragma unroll
            for (int i = 0; i < 16; ++i) {
                const float4 t4 = *(const float4*)(src + (i * 4 + bsub) * 1024 + k0 + kk4);
                vc[i][0] = t4.x; vc[i][1] = t4.y; vc[i][2] = t4.z; vc[i][3] = t4.w;
            }
            STAGE_WRITE_COMPUTE(vc, c);
        }
    }
}

extern "C" __global__ void rnn_init(int* __restrict__ c) {
    const int i = blockIdx.x * blockDim.x + threadIdx.x;
    if (i < 2 * NSH * TT) c[i] = 0;
}

extern "C" __global__ void __launch_bounds__(256, 1)
rnn_persist(const float* __restrict__ x,      // [T][B][IN]
            const float* __restrict__ h0init, // [2][B][H]
            const float* __restrict__ Wih0, const float* __restrict__ bih0,
            const float* __restrict__ Whh0, const float* __restrict__ bhh0,
            const float* __restrict__ Wih1, const float* __restrict__ bih1,
            const float* __restrict__ Whh1, const float* __restrict__ bhh1,
            float* __restrict__ out,          // [T][B][H] then [2][B][H]
            int* __restrict__ c0, int* __restrict__ c1,  // [NSH][TT] shards each
            float* __restrict__ ring)         // [RING_D][B][H]
{
    extern __shared__ float lds[];
    float* Wt    = lds;                      // 16384 floats
    float* buf   = lds + ROWS * KK;          // 4*64*WSTRIDE
    float* parts = buf + 4 * 64 * WSTRIDE;   // 4*64*8

    const int wg   = blockIdx.x;
    const bool isL1 = (wg >= NWGL);
    const int g    = isL1 ? wg - NWGL : wg;
    const int rbase = g * ROWS;
    const int sh   = g & (NSH - 1);          // this WG's counter shard
    const int tid  = threadIdx.x;
    const int wv   = tid >> 6;
    const int lane = tid & 63;
    const int kq   = wv * 256;
    float* bufW = buf + wv * (64 * WSTRIDE);

    // Load this WG's weight rows into LDS once, TRANSPOSED: Wt[k][r].
    const float* Wa = isL1 ? Wih1 : Wih0;    // k-half 0 (input half)
    const float* Wb = isL1 ? Whh1 : Whh0;    // k-half 1 (recurrent half)
    for (int idx = tid; idx < ROWS * 1024; idx += 256) {
        const int r = idx >> 10;
        const int k = idx & 1023;
        Wt[(size_t)k * 8 + r]          = Wa[(size_t)(rbase + r) * HH + k];
        Wt[(size_t)(1024 + k) * 8 + r] = Wb[(size_t)(rbase + r) * HH + k];
    }
    const int er = tid & 7;  // output row (same for tid and tid+256)
    const float bsum = isL1 ? (bih1[rbase + er] + bhh1[rbase + er])
                            : (bih0[rbase + er] + bhh0[rbase + er]);
    __syncthreads();

    const int gk = lane >> 4;   // this lane's k-group (for the slot select)

    for (int t = 0; t < TT; ++t) {
        float acc[4][8];
        #pragma unroll
        for (int s = 0; s < 4; ++s)
            #pragma unroll
            for (int r = 0; r < 8; ++r) acc[s][r] = 0.f;

        if (!isL1) {
            // Phase A: x[t] half — no dependency, hides the wait below.
            stage_and_accum<false>(x + (size_t)t * BH, Wt, bufW, kq, 0, lane, acc);
            // Sharded wait: wave 0, lanes 0-7 poll c0[t-1] shards, 8-15 ring shards.
            if (wv == 0) {
                int* a = nullptr;
                if (lane < 8) { if (t >= 1) a = c0 + lane * TT + (t - 1); }
                else if (lane < 16 && t >= RING_D) a = c1 + (lane - 8) * TT + (t - RING_D);
                if (a) spin_ge(a, SHTGT);
            }
            __syncthreads();
            // Phase B: h0[t-1] half (recurrent, W_hh0 => wof 1024), sc1 reads
            const float* hp = (t == 0) ? h0init
                                       : ring + (size_t)((t - 1) % RING_D) * BH;
            stage_and_accum<true>(hp, Wt, bufW, kq, 1024, lane, acc);
        } else {
            if (wv == 0 && lane < 8 && t >= 1)
                spin_ge(c1 + lane * TT + (t - 1), SHTGT);   // h1[t-1] ready
            __syncthreads();
            // Phase A: h1[t-1] half (recurrent, W_hh1 => wof 1024), sc1 reads
            const float* hp = (t == 0) ? (h0init + BH)
                                       : (out + (size_t)(t - 1) * BH);
            stage_and_accum<true>(hp, Wt, bufW, kq, 1024, lane, acc);
            if (wv == 0 && lane < 8)
                spin_ge(c0 + lane * TT + t, SHTGT);         // h0[t] ready
            __syncthreads();
            // Phase B: h0[t] half (input half, W_ih1 => wof 0), sc1 reads
            stage_and_accum<true>(ring + (size_t)(t % RING_D) * BH, Wt, bufW, kq, 0, lane, acc);
        }

        // Reduce over the 4 k-groups: lanes differing in bits 4,5 hold partials
        // of the same (b-slot, r). After both rounds every lane has full sums.
        float outv[8];
        #pragma unroll
        for (int r = 0; r < 8; ++r) {
            #pragma unroll
            for (int s = 0; s < 4; ++s) {
                float v = acc[s][r];
                v += __shfl_xor(v, 16, 64);
                v += __shfl_xor(v, 32, 64);
                acc[s][r] = v;
            }
            // slot-select s == gk with static indices (rule #20: no runtime idx)
            float v = acc[0][r];
            if (gk == 1) v = acc[1][r];
            if (gk == 2) v = acc[2][r];
            if (gk == 3) v = acc[3][r];
            outv[r] = v;
        }

        // Cross-wave reduction: partials [w][b][r]; this lane's b == lane.
        float* pw = parts + (size_t)(wv * 64 + lane) * ROWS;
        *(float4*)(pw + 0) = make_float4(outv[0], outv[1], outv[2], outv[3]);
        *(float4*)(pw + 4) = make_float4(outv[4], outv[5], outv[6], outv[7]);
        __syncthreads();

        for (int o = tid; o < 512; o += 256) {
            const int b = o >> 3;
            const int r = o & 7;
            const float s = parts[o] + parts[o + 512] + parts[o + 1024] + parts[o + 1536] + bsum;
            const float hv = tanhf(s);
            const int col = rbase + r;
            if (!isL1) {
                st_agent(ring + (size_t)(t % RING_D) * BH + b * HH + col, hv);
                if (t == TT - 1) st_agent(out + (size_t)TT * BH + b * HH + col, hv);      // h0_n
            } else {
                st_agent(out + (size_t)t * BH + b * HH + col, hv);                        // outputs
                if (t == TT - 1) st_agent(out + (size_t)TT * BH + BH + b * HH + col, hv); // h1_n
            }
        }
        // __syncthreads drains vmcnt(0) per wave before s_barrier => after the
        // barrier ALL waves' sc1 write-throughs are at the coherence point.
        __syncthreads();
        if (tid == 0) {
            asm volatile("s_waitcnt vmcnt(0)" ::: "memory");  // belt-and-braces
            __hip_atomic_fetch_add((isL1 ? c1 : c0) + sh * TT + t, 1,
                                   __ATOMIC_RELAXED, __HIP_MEMORY_SCOPE_AGENT);
        }
    }
}

extern "C" void kernel_launch(void* const* d_in, const int* in_sizes, int n_in,
                              void* d_out, int out_size, void* d_ws, size_t ws_size,
                              hipStream_t stream) {
    const float* x    = (const float*)d_in[0];
    const float* h0i  = (const float*)d_in[1];
    const float* Wih0 = (const float*)d_in[2];
    const float* bih0 = (const float*)d_in[3];
    const float* Whh0 = (const float*)d_in[4];
    const float* bhh0 = (const float*)d_in[5];
    const float* Wih1 = (const float*)d_in[6];
    const float* bih1 = (const float*)d_in[7];
    const float* Whh1 = (const float*)d_in[8];
    const float* bhh1 = (const float*)d_in[9];
    float* out = (float*)d_out;

    int*   c0   = (int*)d_ws;                        // [NSH][TT] = 16 KB
    int*   c1   = c0 + NSH * TT;                     // [NSH][TT] = 16 KB
    float* ring = (float*)((char*)d_ws + 65536);     // [RING_D][B][H] = 2 MB

    (void)hipFuncSetAttribute((const void*)rnn_persist,
                              hipFuncAttributeMaxDynamicSharedMemorySize,
                              LDS_FLOATS * 4);

    rnn_init<<<32, 256, 0, stream>>>(c0);
    rnn_persist<<<256, 256, LDS_FLOATS * 4, stream>>>(
        x, h0i, Wih0, bih0, Whh0, bhh0, Wih1, bih1, Whh1, bhh1,
        out, c0, c1, ring);
}

// Round 6
// 12540.202 us; speedup vs baseline: 2.0598x; 1.0661x over previous
//
#include <hip/hip_runtime.h>
#include <math.h>

#define TT 512
#define BB 64
#define HH 1024
#define KK 2048          // IN + H
#define NWGL 128         // WGs per layer
#define ROWS 8           // H rows per WG
#define RING_D 8         // h0 ring depth
#define BH (BB*HH)       // 65536 floats per timestep
#define WSTRIDE 76       // staging row stride (floats): 16B-aligned, 2-way-free banks
#define FSTR 4           // flag padding: 4 ints = 16B per WG flag

// LDS layout (floats):
//   Wt    [KK][8]           = 16384  (64 KB, weights TRANSPOSED: Wt[k][r], resident)
//   buf   [4 waves][64][76] = 19456  (76 KB, UN-transposed [b][k] chunk staging)
//   parts [4][64][ROWS]     = 2048   (8 KB, cross-wave partial sums)
#define LDS_FLOATS (16384 + 4*64*WSTRIDE + 2048)   // 148 KB

typedef float floatx4 __attribute__((ext_vector_type(4)));

// ---------------------------------------------------------------------------
// R6: R5 (sharded counters + pipelined sc1) matched prediction: 25.8->13.4ms.
// Remaining 26us/step with ALL pipes idle (HBM 2%, VALU 25%, LDS ~12%):
// still sync-stall. Theory: the per-shard fetch_adds are AGENT-SCOPE RMWs to
// lines that ~256 WGs poll concurrently; each RMW serializes against the read
// stream at the L3 bank -> 16 serialized contended RMWs ~2.5-8us per publish
// event, x2 events on the critical path per step.
//
// Fix: NO RMWs. Per-WG 16B-padded flag words; publish = one plain sc1 store
// of (t+1) (single writer per word, no atomicity needed; data already drained
// by the pre-barrier vmcnt(0)). Wait = wave0's 64 lanes poll all 128 flags in
// PARALLEL (2 loads/lane + __all ballot). Compute core, staging pipeline, and
// coherence protocol are byte-identical to R5. One variable.
// Falsifier: <10% move => broadcast-BW-bound (96MB/step via L3) -> R7 ROWS=16.
// ---------------------------------------------------------------------------

__device__ __forceinline__ int ld_flag(const int* p) {
    return __hip_atomic_load(p, __ATOMIC_RELAXED, __HIP_MEMORY_SCOPE_AGENT);
}

// Agent-scope (sc1) scalar store: write-through to the coherence point.
__device__ __forceinline__ void st_agent(float* p, float v) {
    __hip_atomic_store(p, v, __ATOMIC_RELAXED, __HIP_MEMORY_SCOPE_AGENT);
}

#define FMA8(s, iv) \
    acc[s][0] += wA.x*(iv); acc[s][1] += wA.y*(iv); acc[s][2] += wA.z*(iv); acc[s][3] += wA.w*(iv); \
    acc[s][4] += wB.x*(iv); acc[s][5] += wB.y*(iv); acc[s][6] += wB.z*(iv); acc[s][7] += wB.w*(iv);

// Write one staged chunk (16 float4 regs) to LDS and run its 16 k-steps.
#define STAGE_WRITE_COMPUTE(v, c) do {                                         \
    const int k0_ = kq + (c) * 64;                                             \
    _Pragma("unroll")                                                          \
    for (int i = 0; i < 16; ++i) {                                             \
        const int b = i * 4 + bsub;                                            \
        *(float4*)(bufW + b * WSTRIDE + kk4) =                                 \
            make_float4(v[i][0], v[i][1], v[i][2], v[i][3]);                   \
    }                                                                          \
    const float* wt = Wt + (size_t)(wof + k0_ + g) * 8;                        \
    const float* bw = bufW + b16 * WSTRIDE + g;                                \
    _Pragma("unroll 4")                                                        \
    for (int j = 0; j < 16; ++j) {                                             \
        const float4 wA = *(const float4*)(wt + j * 32);                       \
        const float4 wB = *(const float4*)(wt + j * 32 + 4);                   \
        const float i0 = bw[j * 4];                                            \
        const float i1 = bw[j * 4 + 16 * WSTRIDE];                             \
        const float i2 = bw[j * 4 + 32 * WSTRIDE];                             \
        const float i3 = bw[j * 4 + 48 * WSTRIDE];                             \
        FMA8(0, i0) FMA8(1, i1) FMA8(2, i2) FMA8(3, i3)                        \
    }                                                                          \
} while (0)

#define ISSUE16(v, c) do {                                                     \
    _Pragma("unroll")                                                          \
    for (int i = 0; i < 16; ++i) {                                             \
        const float* p = src + (i * 4 + bsub) * 1024 + kq + (c) * 64 + kk4;    \
        asm volatile("global_load_dwordx4 %0, %1, off sc1"                     \
                     : "=v"(v[i]) : "v"(p));                                   \
    }                                                                          \
} while (0)

// Stage one 1024-wide half (this wave's 256-k quarter, 4 chunks of 64) into LDS
// as raw [b][k] rows (stride WSTRIDE), then accumulate 4b x 8r with k-interleave.
// BYPASS: sc1 reads, ping-pong pipelined with counted vmcnt (1 exposed latency).
template<bool BYPASS>
__device__ __forceinline__ void stage_and_accum(
    const float* __restrict__ src,   // [BB][1024], row-major
    const float* __restrict__ Wt,    // LDS [KK][8] transposed weights
    float* __restrict__ bufW,        // this wave's [64][WSTRIDE] region
    int kq,                          // wave quarter offset: 256*wave
    int wof,                         // W k-offset for this half: 0 or 1024
    int lane,
    float acc[4][8])
{
    const int bsub = lane >> 4;          // 0..3 (also the k-group g)
    const int kk4  = (lane & 15) * 4;    // 0..60
    const int b16  = lane & 15;
    const int g    = bsub;
    if (BYPASS) {
        floatx4 vA[16], vB[16];          // static ping-pong (rule #20: no runtime idx)
        ISSUE16(vA, 0);                                  // A(c0) in flight
        ISSUE16(vB, 1);                                  // +B(c1): 32 out
        asm volatile("s_waitcnt vmcnt(16)" ::: "memory");  // A(c0) arrived
        __builtin_amdgcn_sched_barrier(0);
        STAGE_WRITE_COMPUTE(vA, 0);                      // B(c1) hides under this
        ISSUE16(vA, 2);                                  // +A(c2): 32 out
        asm volatile("s_waitcnt vmcnt(16)" ::: "memory");  // B(c1) arrived
        __builtin_amdgcn_sched_barrier(0);
        STAGE_WRITE_COMPUTE(vB, 1);                      // A(c2) hides under this
        ISSUE16(vB, 3);                                  // +B(c3): 32 out
        asm volatile("s_waitcnt vmcnt(16)" ::: "memory");  // A(c2) arrived
        __builtin_amdgcn_sched_barrier(0);
        STAGE_WRITE_COMPUTE(vA, 2);                      // B(c3) hides under this
        asm volatile("s_waitcnt vmcnt(0)" ::: "memory");   // B(c3) arrived
        __builtin_amdgcn_sched_barrier(0);
        STAGE_WRITE_COMPUTE(vB, 3);
    } else {
        #pragma unroll 1                 // no cross-chunk load hoisting (VGPR cap!)
        for (int c = 0; c < 4; ++c) {
            const int k0 = kq + c * 64;
            floatx4 vc[16];
            #pragma unroll
            for (int i = 0; i < 16; ++i) {
                const float4 t4 = *(const float4*)(src + (i * 4 + bsub) * 1024 + k0 + kk4);
                vc[i][0] = t4.x; vc[i][1] = t4.y; vc[i][2] = t4.z; vc[i][3] = t4.w;
            }
            STAGE_WRITE_COMPUTE(vc, c);
        }
    }
}

extern "C" __global__ void rnn_init(int* __restrict__ c) {
    const int i = blockIdx.x * blockDim.x + threadIdx.x;
    if (i < 2 * NWGL * FSTR) c[i] = 0;
}

extern "C" __global__ void __launch_bounds__(256, 1)
rnn_persist(const float* __restrict__ x,      // [T][B][IN]
            const float* __restrict__ h0init, // [2][B][H]
            const float* __restrict__ Wih0, const float* __restrict__ bih0,
            const float* __restrict__ Whh0, const float* __restrict__ bhh0,
            const float* __restrict__ Wih1, const float* __restrict__ bih1,
            const float* __restrict__ Whh1, const float* __restrict__ bhh1,
            float* __restrict__ out,          // [T][B][H] then [2][B][H]
            int* __restrict__ f0, int* __restrict__ f1,  // per-WG flags [NWGL][FSTR]
            float* __restrict__ ring)         // [RING_D][B][H]
{
    extern __shared__ float lds[];
    float* Wt    = lds;                      // 16384 floats
    float* buf   = lds + ROWS * KK;          // 4*64*WSTRIDE
    float* parts = buf + 4 * 64 * WSTRIDE;   // 4*64*8

    const int wg   = blockIdx.x;
    const bool isL1 = (wg >= NWGL);
    const int g    = isL1 ? wg - NWGL : wg;
    const int rbase = g * ROWS;
    const int tid  = threadIdx.x;
    const int wv   = tid >> 6;
    const int lane = tid & 63;
    const int kq   = wv * 256;
    float* bufW = buf + wv * (64 * WSTRIDE);

    // Load this WG's weight rows into LDS once, TRANSPOSED: Wt[k][r].
    const float* Wa = isL1 ? Wih1 : Wih0;    // k-half 0 (input half)
    const float* Wb = isL1 ? Whh1 : Whh0;    // k-half 1 (recurrent half)
    for (int idx = tid; idx < ROWS * 1024; idx += 256) {
        const int r = idx >> 10;
        const int k = idx & 1023;
        Wt[(size_t)k * 8 + r]          = Wa[(size_t)(rbase + r) * HH + k];
        Wt[(size_t)(1024 + k) * 8 + r] = Wb[(size_t)(rbase + r) * HH + k];
    }
    const int er = tid & 7;  // output row (same for tid and tid+256)
    const float bsum = isL1 ? (bih1[rbase + er] + bhh1[rbase + er])
                            : (bih0[rbase + er] + bhh0[rbase + er]);
    __syncthreads();

    const int gk = lane >> 4;   // this lane's k-group (for the slot select)
    // Per-lane flag pointers: wave0's 64 lanes cover all 128 WGs of a layer.
    const int* p0a = f0 + lane * FSTR;
    const int* p0b = f0 + (lane + 64) * FSTR;
    const int* p1a = f1 + lane * FSTR;
    const int* p1b = f1 + (lane + 64) * FSTR;

    for (int t = 0; t < TT; ++t) {
        float acc[4][8];
        #pragma unroll
        for (int s = 0; s < 4; ++s)
            #pragma unroll
            for (int r = 0; r < 8; ++r) acc[s][r] = 0.f;

        if (!isL1) {
            // Phase A: x[t] half — no dependency, hides the wait below.
            stage_and_accum<false>(x + (size_t)t * BH, Wt, bufW, kq, 0, lane, acc);
            // Parallel-lane wait: all 128 f0 >= t (h0[t-1]) and, if ring wraps,
            // all 128 f1 >= t-RING_D+1 (slot consumed). No RMWs anywhere.
            if (wv == 0 && t >= 1) {
                const int tr = t - RING_D + 1;
                int it = 0;
                for (;;) {
                    bool ok = (ld_flag(p0a) >= t) & (ld_flag(p0b) >= t);
                    if (t >= RING_D)
                        ok = ok & (ld_flag(p1a) >= tr) & (ld_flag(p1b) >= tr);
                    if (__all(ok)) break;
                    __builtin_amdgcn_s_sleep(2);
                    if (++it > (1 << 15)) break;   // failsafe: fail loud, never hang
                }
            }
            __syncthreads();
            // Phase B: h0[t-1] half (recurrent, W_hh0 => wof 1024), sc1 reads
            const float* hp = (t == 0) ? h0init
                                       : ring + (size_t)((t - 1) % RING_D) * BH;
            stage_and_accum<true>(hp, Wt, bufW, kq, 1024, lane, acc);
        } else {
            if (wv == 0 && t >= 1) {
                int it = 0;
                for (;;) {                      // h1[t-1] ready: all f1 >= t
                    if (__all((ld_flag(p1a) >= t) & (ld_flag(p1b) >= t))) break;
                    __builtin_amdgcn_s_sleep(2);
                    if (++it > (1 << 15)) break;
                }
            }
            __syncthreads();
            // Phase A: h1[t-1] half (recurrent, W_hh1 => wof 1024), sc1 reads
            const float* hp = (t == 0) ? (h0init + BH)
                                       : (out + (size_t)(t - 1) * BH);
            stage_and_accum<true>(hp, Wt, bufW, kq, 1024, lane, acc);
            if (wv == 0) {
                const int tp = t + 1;
                int it = 0;
                for (;;) {                      // h0[t] ready: all f0 >= t+1
                    if (__all((ld_flag(p0a) >= tp) & (ld_flag(p0b) >= tp))) break;
                    __builtin_amdgcn_s_sleep(2);
                    if (++it > (1 << 15)) break;
                }
            }
            __syncthreads();
            // Phase B: h0[t] half (input half, W_ih1 => wof 0), sc1 reads
            stage_and_accum<true>(ring + (size_t)(t % RING_D) * BH, Wt, bufW, kq, 0, lane, acc);
        }

        // Reduce over the 4 k-groups: lanes differing in bits 4,5 hold partials
        // of the same (b-slot, r). After both rounds every lane has full sums.
        float outv[8];
        #pragma unroll
        for (int r = 0; r < 8; ++r) {
            #pragma unroll
            for (int s = 0; s < 4; ++s) {
                float v = acc[s][r];
                v += __shfl_xor(v, 16, 64);
                v += __shfl_xor(v, 32, 64);
                acc[s][r] = v;
            }
            // slot-select s == gk with static indices (rule #20: no runtime idx)
            float v = acc[0][r];
            if (gk == 1) v = acc[1][r];
            if (gk == 2) v = acc[2][r];
            if (gk == 3) v = acc[3][r];
            outv[r] = v;
        }

        // Cross-wave reduction: partials [w][b][r]; this lane's b == lane.
        float* pw = parts + (size_t)(wv * 64 + lane) * ROWS;
        *(float4*)(pw + 0) = make_float4(outv[0], outv[1], outv[2], outv[3]);
        *(float4*)(pw + 4) = make_float4(outv[4], outv[5], outv[6], outv[7]);
        __syncthreads();

        for (int o = tid; o < 512; o += 256) {
            const int b = o >> 3;
            const int r = o & 7;
            const float s = parts[o] + parts[o + 512] + parts[o + 1024] + parts[o + 1536] + bsum;
            const float hv = tanhf(s);
            const int col = rbase + r;
            if (!isL1) {
                st_agent(ring + (size_t)(t % RING_D) * BH + b * HH + col, hv);
                if (t == TT - 1) st_agent(out + (size_t)TT * BH + b * HH + col, hv);      // h0_n
            } else {
                st_agent(out + (size_t)t * BH + b * HH + col, hv);                        // outputs
                if (t == TT - 1) st_agent(out + (size_t)TT * BH + BH + b * HH + col, hv); // h1_n
            }
        }
        // __syncthreads drains vmcnt(0) per wave before s_barrier => after the
        // barrier ALL waves' sc1 write-throughs are at the coherence point.
        __syncthreads();
        if (tid == 0) {
            asm volatile("s_waitcnt vmcnt(0)" ::: "memory");  // belt-and-braces (free)
            // Publish: plain sc1 store to THIS WG's private flag word. No RMW.
            __hip_atomic_store((isL1 ? f1 : f0) + g * FSTR, t + 1,
                               __ATOMIC_RELAXED, __HIP_MEMORY_SCOPE_AGENT);
        }
    }
}

extern "C" void kernel_launch(void* const* d_in, const int* in_sizes, int n_in,
                              void* d_out, int out_size, void* d_ws, size_t ws_size,
                              hipStream_t stream) {
    const float* x    = (const float*)d_in[0];
    const float* h0i  = (const float*)d_in[1];
    const float* Wih0 = (const float*)d_in[2];
    const float* bih0 = (const float*)d_in[3];
    const float* Whh0 = (const float*)d_in[4];
    const float* bhh0 = (const float*)d_in[5];
    const float* Wih1 = (const float*)d_in[6];
    const float* bih1 = (const float*)d_in[7];
    const float* Whh1 = (const float*)d_in[8];
    const float* bhh1 = (const float*)d_in[9];
    float* out = (float*)d_out;

    int*   f0   = (int*)d_ws;                        // [NWGL][FSTR] = 2 KB
    int*   f1   = f0 + NWGL * FSTR;                  // [NWGL][FSTR] = 2 KB
    float* ring = (float*)((char*)d_ws + 65536);     // [RING_D][B][H] = 2 MB

    (void)hipFuncSetAttribute((const void*)rnn_persist,
                              hipFuncAttributeMaxDynamicSharedMemorySize,
                              LDS_FLOATS * 4);

    rnn_init<<<4, 256, 0, stream>>>(f0);
    rnn_persist<<<256, 256, LDS_FLOATS * 4, stream>>>(
        x, h0i, Wih0, bih0, Whh0, bhh0, Wih1, bih1, Whh1, bhh1,
        out, f0, f1, ring);
}